// Round 9
// baseline (475.938 us; speedup 1.0000x reference)
//
#include <hip/hip_runtime.h>

// Problem constants (from reference)
constexpr int N_PART = 100000;
constexpr int N_EDGE = 6400000;
constexpr float SUPPORT = 0.05f;
constexpr float PI_F = 3.14159265358979323846f;

// ===========================================================================
// Sorted path: block-local counting sort (records staged in LDS SoA, all
// global traffic coalesced), then bin-owner LDS accumulation.
// R9: CH=2048 (exact divisor of E -> no tail), 256 thr, 4 blocks/CU,
// 8 edges/thread fully unrolled for memory-level parallelism.
// ===========================================================================
constexpr int CH_LOG2 = 11;
constexpr int CH      = 1 << CH_LOG2;            // 2048 edges per sort chunk
constexpr int NCH     = N_EDGE / CH;             // 3125 chunks (exact)
constexpr int BIN_LOG2 = 13;
constexpr int BINSZ   = 1 << BIN_LOG2;           // 8192 particles per bin
constexpr int NBIN    = (N_PART + BINSZ - 1) / BINSZ;  // 13 bins
constexpr int G_MAX   = 39;                      // partial groups (13*39=507 blocks)
constexpr int ST_NW   = 4;                       // l1_sort waves (256 threads)
constexpr int E_PER   = CH / 256;                // 8 edges per thread

__global__ __launch_bounds__(256) void l1_sort(
    const int* __restrict__ nb,        // [2*E]
    const float* __restrict__ areas,   // [N]
    const float* __restrict__ dens,    // [N]
    const float* __restrict__ rest,    // [N]
    const float* __restrict__ q,       // [E]
    const float2* __restrict__ dist,   // [E]
    unsigned* __restrict__ gpack,
    float2* __restrict__ gpay1,
    float2* __restrict__ gpay2,
    unsigned* __restrict__ btab)       // [NCH*16] u32
{
    __shared__ unsigned rec_pack[CH];         // 8 KB each, SoA
    __shared__ float    rec_q[CH];
    __shared__ float    rec_dx[CH];
    __shared__ float    rec_dy[CH];
    __shared__ unsigned hist[ST_NW * NBIN];
    __shared__ unsigned curw[ST_NW * NBIN];
    __shared__ unsigned base[NBIN + 1];

    const int t   = blockIdx.x;
    const int c0  = t * CH;                   // len == CH always (exact divisor)
    const int tid = threadIdx.x;
    const int wid = tid >> 6;                 // 4 waves

    for (int k = tid; k < ST_NW * NBIN; k += 256) hist[k] = 0u;
    __syncthreads();

    // Phase 1: batched coalesced read of 8 i-values, per-wave histogram.
    unsigned iv[E_PER];
    #pragma unroll
    for (int k = 0; k < E_PER; ++k)
        iv[k] = (unsigned)nb[c0 + tid + k * 256];
    #pragma unroll
    for (int k = 0; k < E_PER; ++k)
        atomicAdd(&hist[wid * NBIN + (iv[k] >> BIN_LOG2)], 1u);
    __syncthreads();

    // Serial scan: bin bases + per-(wave,bin) cursors (13*4 = 52 iters)
    if (tid == 0) {
        unsigned run = 0;
        for (int b = 0; b < NBIN; ++b) {
            base[b] = run;
            for (int w = 0; w < ST_NW; ++w) {
                curw[w * NBIN + b] = run;
                run += hist[w * NBIN + b];
            }
        }
        base[NBIN] = run;   // == CH
    }
    __syncthreads();
    if (tid < NBIN)  btab[t * 16 + tid]  = base[tid];
    if (tid == NBIN) btab[t * 16 + NBIN] = (unsigned)CH;

    // Phase 2: batched coalesced reads of j/q/dist; rank via own wave's
    // cursor; SoA scatter into LDS.
    unsigned jv[E_PER];
    float    qv[E_PER], dxv[E_PER], dyv[E_PER];
    #pragma unroll
    for (int k = 0; k < E_PER; ++k) {
        int idx = tid + k * 256;
        jv[k] = (unsigned)nb[N_EDGE + c0 + idx];
        qv[k] = q[c0 + idx];
        float2 d = dist[c0 + idx];
        dxv[k] = d.x; dyv[k] = d.y;
    }
    #pragma unroll
    for (int k = 0; k < E_PER; ++k) {
        unsigned bin = iv[k] >> BIN_LOG2;
        unsigned r = atomicAdd(&curw[wid * NBIN + bin], 1u) & (CH - 1);
        rec_pack[r] = ((iv[k] & (BINSZ - 1)) << 17) | jv[k];
        rec_q[r]    = qv[k];
        rec_dx[r]   = dxv[k];
        rec_dy[r]   = dyv[k];
    }
    __syncthreads();

    // Phase 3: batched LDS reads + batched L2-resident gathers; coalesced out.
    const float Cw = 7.0f / (PI_F * SUPPORT * SUPPORT);
    unsigned pk[E_PER]; float q3[E_PER], dx3[E_PER], dy3[E_PER];
    float ar[E_PER], de[E_PER], re[E_PER];
    #pragma unroll
    for (int k = 0; k < E_PER; ++k) {
        int p = tid + k * 256;
        pk[k] = rec_pack[p];
        q3[k] = rec_q[p]; dx3[k] = rec_dx[p]; dy3[k] = rec_dy[p];
    }
    #pragma unroll
    for (int k = 0; k < E_PER; ++k) {
        unsigned j = pk[k] & 0x1FFFFu;
        ar[k] = areas[j]; de[k] = dens[j]; re[k] = rest[j];
    }
    #pragma unroll
    for (int k = 0; k < E_PER; ++k) {
        float qq = q3[k];
        float omq  = fmaxf(1.0f - qq, 0.0f);
        float dWdq = Cw * (-20.0f * qq * omq * omq * omq) * (1.0f / SUPPORT);
        float s    = SUPPORT * (ar[k] / de[k]) * dWdq;

        float qm1  = qq - 1.0f;
        float tt   = qm1 * qm1 * qm1 * qq * qq * qq;
        float kern = (qq <= 0.5f) ? fmaf(128.0f, tt, 1.0f) : 64.0f * tt;
        float fc   = ar[k] * re[k] * kern;

        int o = c0 + tid + k * 256;
        gpack[o] = pk[k];
        gpay1[o] = make_float2(s * dx3[k], s * dy3[k]);
        gpay2[o] = make_float2(fc * dx3[k], fc * dy3[k]);
    }
}

// --- Pass B: accumulate normals per bin; 4x predicated load batch ---------
__global__ __launch_bounds__(512) void passB(
    const unsigned* __restrict__ btab,
    const unsigned* __restrict__ gpack,
    const float2* __restrict__ gpay1,
    float2* __restrict__ partials,       // [G][NBIN*BINSZ]
    int G)
{
    __shared__ float accx[BINSZ];        // 32 KB
    __shared__ float accy[BINSZ];        // 32 KB
    const int b = blockIdx.x % NBIN;
    const int g = blockIdx.x / NBIN;
    const int wave = threadIdx.x >> 6;
    const int lane = threadIdx.x & 63;

    for (int k = threadIdx.x; k < BINSZ; k += 512) { accx[k] = 0.0f; accy[k] = 0.0f; }
    __syncthreads();

    const int t0 = (int)((long long)g * NCH / G);
    const int t1 = (int)((long long)(g + 1) * NCH / G);
    for (int t = t0 + wave; t < t1; t += 8) {
        const int c0  = t * CH;
        const unsigned ln = min(btab[t * 16 + NBIN], (unsigned)CH);
        unsigned sb = min(btab[t * 16 + b], ln);
        unsigned se = min(btab[t * 16 + b + 1], ln);
        for (unsigned k = sb + lane; k < se; k += 256) {
            unsigned pkv[4]; float px[4], py[4];
            #pragma unroll
            for (int u = 0; u < 4; ++u) {
                unsigned kk = k + (unsigned)(u * 64);
                bool v = kk < se;
                int o = c0 + (int)(v ? kk : k);
                unsigned pw = gpack[o];
                float2 p = gpay1[o];
                pkv[u] = v ? pw : 0u;
                px[u] = v ? p.x : 0.0f;
                py[u] = v ? p.y : 0.0f;
            }
            #pragma unroll
            for (int u = 0; u < 4; ++u) {
                unsigned loc = (pkv[u] >> 17) & (BINSZ - 1);
                atomicAdd(&accx[loc], px[u]);
                atomicAdd(&accy[loc], py[u]);
            }
        }
    }
    __syncthreads();

    float2* __restrict__ dst = partials + (size_t)g * (NBIN * BINSZ) + (size_t)b * BINSZ;
    for (int k = threadIdx.x; k < BINSZ; k += 512)
        dst[k] = make_float2(accx[k], accy[k]);
}

// --- Pass D: acc_i += (n_j - n_i + coh) per edge; 4x predicated batch -----
__global__ __launch_bounds__(512) void passD(
    const unsigned* __restrict__ btab,
    const unsigned* __restrict__ gpack,
    const float2* __restrict__ gpay2,
    const float2* __restrict__ normals,  // [N]
    float2* __restrict__ partials,
    int G)
{
    __shared__ float accx[BINSZ];
    __shared__ float accy[BINSZ];
    const int b = blockIdx.x % NBIN;
    const int g = blockIdx.x / NBIN;
    const int wave = threadIdx.x >> 6;
    const int lane = threadIdx.x & 63;

    for (int k = threadIdx.x; k < BINSZ; k += 512) { accx[k] = 0.0f; accy[k] = 0.0f; }
    __syncthreads();

    const int gbase = b * BINSZ;
    const int t0 = (int)((long long)g * NCH / G);
    const int t1 = (int)((long long)(g + 1) * NCH / G);
    for (int t = t0 + wave; t < t1; t += 8) {
        const int c0  = t * CH;
        const unsigned ln = min(btab[t * 16 + NBIN], (unsigned)CH);
        unsigned sb = min(btab[t * 16 + b], ln);
        unsigned se = min(btab[t * 16 + b + 1], ln);
        for (unsigned k = sb + lane; k < se; k += 256) {
            unsigned pkv[4]; float cx[4], cy[4]; bool vv[4];
            #pragma unroll
            for (int u = 0; u < 4; ++u) {
                unsigned kk = k + (unsigned)(u * 64);
                bool v = kk < se;
                int o = c0 + (int)(v ? kk : k);
                unsigned pw = gpack[o];
                float2 p = gpay2[o];
                vv[u] = v;
                pkv[u] = v ? pw : 0u;
                cx[u] = p.x; cy[u] = p.y;
            }
            float njx[4], njy[4], nix[4], niy[4];
            #pragma unroll
            for (int u = 0; u < 4; ++u) {
                unsigned loc = (pkv[u] >> 17) & (BINSZ - 1);
                unsigned j   = min(pkv[u] & 0x1FFFFu, (unsigned)(N_PART - 1));
                unsigned ii  = min((unsigned)(gbase + loc), (unsigned)(N_PART - 1));
                float2 nj = normals[j];
                float2 ni = normals[ii];
                njx[u] = nj.x; njy[u] = nj.y; nix[u] = ni.x; niy[u] = ni.y;
            }
            #pragma unroll
            for (int u = 0; u < 4; ++u) {
                unsigned loc = (pkv[u] >> 17) & (BINSZ - 1);
                float ax = vv[u] ? (njx[u] - nix[u] + cx[u]) : 0.0f;
                float ay = vv[u] ? (njy[u] - niy[u] + cy[u]) : 0.0f;
                atomicAdd(&accx[loc], ax);
                atomicAdd(&accy[loc], ay);
            }
        }
    }
    __syncthreads();

    float2* __restrict__ dst = partials + (size_t)g * (NBIN * BINSZ) + (size_t)b * BINSZ;
    for (int k = threadIdx.x; k < BINSZ; k += 512)
        dst[k] = make_float2(accx[k], accy[k]);
}

// dst[p] = sum_g partials[g][p]
__global__ __launch_bounds__(256) void reduceG(
    const float2* __restrict__ partials, float2* __restrict__ dst, int G)
{
    int p = blockIdx.x * blockDim.x + threadIdx.x;
    if (p >= N_PART) return;
    float ax = 0.0f, ay = 0.0f;
    for (int g = 0; g < G; ++g) {
        float2 v = partials[(size_t)g * (NBIN * BINSZ) + p];
        ax += v.x; ay += v.y;
    }
    dst[p] = make_float2(ax, ay);
}

// ===========================================================================
// Fallback 1 (R3, proven 631 us): binned multi-read path. Fallback 2: atomics.
// ===========================================================================
constexpr int FB_BSZ_LOG2 = 13;
constexpr int FB_BSZ   = 1 << FB_BSZ_LOG2;
constexpr int FB_NBINS = (N_PART + FB_BSZ - 1) / FB_BSZ;
constexpr int FB_NP_PAD = FB_NBINS * FB_BSZ;
constexpr int FB_C_TARGET = 39;

__global__ __launch_bounds__(1024) void fb_pass1_binned(
    const int* __restrict__ nb, const float* __restrict__ areas,
    const float* __restrict__ dens, const float* __restrict__ q,
    const float2* __restrict__ dist, float* __restrict__ partials, int C)
{
    __shared__ float lds[2 * FB_BSZ];
    const int b = blockIdx.x % FB_NBINS;
    const int c = blockIdx.x / FB_NBINS;
    for (int k = threadIdx.x; k < 2 * FB_BSZ; k += blockDim.x) lds[k] = 0.0f;
    __syncthreads();
    const int start = (int)((long long)c       * (N_EDGE / 4) / C) * 4;
    const int end   = (int)((long long)(c + 1) * (N_EDGE / 4) / C) * 4;
    const int4* __restrict__ nb4 = (const int4*)nb;
    const float Cw = 7.0f / (PI_F * SUPPORT * SUPPORT);
    for (int e = start + (int)threadIdx.x * 4; e < end; e += (int)blockDim.x * 4) {
        int4 iq = nb4[e >> 2];
        #pragma unroll
        for (int k = 0; k < 4; ++k) {
            int iv = (k == 0) ? iq.x : (k == 1) ? iq.y : (k == 2) ? iq.z : iq.w;
            if ((iv >> FB_BSZ_LOG2) == b) {
                int ee = e + k;
                int j  = nb[N_EDGE + ee];
                float qq  = q[ee];
                float fac = areas[j] / dens[j];
                float omq  = fmaxf(1.0f - qq, 0.0f);
                float dWdq = Cw * (-20.0f * qq * omq * omq * omq) * (1.0f / SUPPORT);
                float s = SUPPORT * fac * dWdq;
                float2 d = dist[ee];
                int loc = (iv & (FB_BSZ - 1)) << 1;
                atomicAdd(&lds[loc],     s * d.x);
                atomicAdd(&lds[loc + 1], s * d.y);
            }
        }
    }
    __syncthreads();
    float2* __restrict__ dst = (float2*)partials + (size_t)c * FB_NP_PAD + (size_t)b * FB_BSZ;
    const float2* __restrict__ src = (const float2*)lds;
    for (int k = threadIdx.x; k < FB_BSZ; k += blockDim.x) dst[k] = src[k];
}

__global__ __launch_bounds__(1024) void fb_pass2_binned(
    const int* __restrict__ nb, const float* __restrict__ areas,
    const float* __restrict__ rest, const float* __restrict__ q,
    const float2* __restrict__ dist, const float2* __restrict__ normals,
    float* __restrict__ partials, int C)
{
    __shared__ float lds[2 * FB_BSZ];
    const int b = blockIdx.x % FB_NBINS;
    const int c = blockIdx.x / FB_NBINS;
    for (int k = threadIdx.x; k < 2 * FB_BSZ; k += blockDim.x) lds[k] = 0.0f;
    __syncthreads();
    const int start = (int)((long long)c       * (N_EDGE / 4) / C) * 4;
    const int end   = (int)((long long)(c + 1) * (N_EDGE / 4) / C) * 4;
    const int4* __restrict__ nb4 = (const int4*)nb;
    for (int e = start + (int)threadIdx.x * 4; e < end; e += (int)blockDim.x * 4) {
        int4 iq = nb4[e >> 2];
        #pragma unroll
        for (int k = 0; k < 4; ++k) {
            int iv = (k == 0) ? iq.x : (k == 1) ? iq.y : (k == 2) ? iq.z : iq.w;
            if ((iv >> FB_BSZ_LOG2) == b) {
                int ee = e + k;
                int j  = nb[N_EDGE + ee];
                float2 ni = normals[iv];
                float2 nj = normals[j];
                float qq  = q[ee];
                float fc  = areas[j] * rest[j];
                float qm1 = qq - 1.0f;
                float t   = qm1 * qm1 * qm1 * qq * qq * qq;
                float kern = (qq <= 0.5f) ? fmaf(128.0f, t, 1.0f) : 64.0f * t;
                float2 d = dist[ee];
                int loc = (iv & (FB_BSZ - 1)) << 1;
                atomicAdd(&lds[loc],     -(ni.x - nj.x) + fc * kern * d.x);
                atomicAdd(&lds[loc + 1], -(ni.y - nj.y) + fc * kern * d.y);
            }
        }
    }
    __syncthreads();
    float2* __restrict__ dst = (float2*)partials + (size_t)c * FB_NP_PAD + (size_t)b * FB_BSZ;
    const float2* __restrict__ src = (const float2*)lds;
    for (int k = threadIdx.x; k < FB_BSZ; k += blockDim.x) dst[k] = src[k];
}

__global__ __launch_bounds__(256) void fb_reduce_partials(
    const float* __restrict__ partials, float* __restrict__ dst, int C)
{
    int p = blockIdx.x * blockDim.x + threadIdx.x;
    if (p >= N_PART) return;
    const float2* __restrict__ p2 = (const float2*)partials;
    float ax = 0.0f, ay = 0.0f;
    for (int c = 0; c < C; ++c) {
        float2 v = p2[(size_t)c * FB_NP_PAD + p];
        ax += v.x; ay += v.y;
    }
    ((float2*)dst)[p] = make_float2(ax, ay);
}

__global__ __launch_bounds__(256) void fb_zero2(float* __restrict__ a,
                                                float* __restrict__ b, int n) {
    int idx = blockIdx.x * blockDim.x + threadIdx.x;
    if (idx < n) { a[idx] = 0.0f; b[idx] = 0.0f; }
}

__global__ __launch_bounds__(256) void fb_pass1_atomic(
    const int* __restrict__ nb, const float* __restrict__ areas,
    const float* __restrict__ dens, const float* __restrict__ q,
    const float2* __restrict__ dist, float* __restrict__ normals)
{
    int e = blockIdx.x * blockDim.x + threadIdx.x;
    if (e >= N_EDGE) return;
    int i = nb[e];
    int j = nb[N_EDGE + e];
    float qq  = q[e];
    float fac = areas[j] / dens[j];
    const float Cw = 7.0f / (PI_F * SUPPORT * SUPPORT);
    float omq  = fmaxf(1.0f - qq, 0.0f);
    float dWdq = Cw * (-20.0f * qq * omq * omq * omq) * (1.0f / SUPPORT);
    float s = SUPPORT * fac * dWdq;
    float2 d = dist[e];
    atomicAdd(&normals[2 * i],     s * d.x);
    atomicAdd(&normals[2 * i + 1], s * d.y);
}

__global__ __launch_bounds__(256) void fb_pass2_atomic(
    const int* __restrict__ nb, const float* __restrict__ areas,
    const float* __restrict__ rest, const float* __restrict__ q,
    const float2* __restrict__ dist, const float2* __restrict__ normals,
    float* __restrict__ out)
{
    int e = blockIdx.x * blockDim.x + threadIdx.x;
    if (e >= N_EDGE) return;
    int i = nb[e];
    int j = nb[N_EDGE + e];
    float2 ni = normals[i];
    float2 nj = normals[j];
    float qq  = q[e];
    float fc  = areas[j] * rest[j];
    float qm1 = qq - 1.0f;
    float t   = qm1 * qm1 * qm1 * qq * qq * qq;
    float kern = (qq <= 0.5f) ? fmaf(128.0f, t, 1.0f) : 64.0f * t;
    float2 d = dist[e];
    atomicAdd(&out[2 * i],     -(ni.x - nj.x) + fc * kern * d.x);
    atomicAdd(&out[2 * i + 1], -(ni.y - nj.y) + fc * kern * d.y);
}

// ===========================================================================
extern "C" void kernel_launch(void* const* d_in, const int* in_sizes, int n_in,
                              void* d_out, int out_size, void* d_ws, size_t ws_size,
                              hipStream_t stream) {
    const int*   nb    = (const int*)d_in[0];     // [2*E]
    const float* areas = (const float*)d_in[1];   // [N]
    const float* dens  = (const float*)d_in[2];   // [N]
    const float* rest  = (const float*)d_in[3];   // [N]
    const float* q     = (const float*)d_in[4];   // [E]
    const float* dist  = (const float*)d_in[5];   // [E,2]
    float* out = (float*)d_out;                   // [N,2]

    // --- Sorted-path workspace layout ---
    size_t off = 0;
    auto take = [&](size_t bytes) { size_t o = off; off += (bytes + 255) & ~(size_t)255; return o; };
    size_t o_pack    = take((size_t)N_EDGE * sizeof(unsigned));
    size_t o_pay1    = take((size_t)N_EDGE * sizeof(float2));
    size_t o_pay2    = take((size_t)N_EDGE * sizeof(float2));
    size_t o_btab    = take((size_t)NCH * 16 * sizeof(unsigned));
    size_t o_normals = take((size_t)N_PART * sizeof(float2));
    size_t base_need = off;
    const size_t per_g = (size_t)(NBIN * BINSZ) * sizeof(float2);

    int G = 0;
    if (ws_size > base_need) {
        G = (int)((ws_size - base_need) / per_g);
        if (G > G_MAX) G = G_MAX;
    }

    char* ws = (char*)d_ws;

    if (G >= 6) {
        unsigned* gpack   = (unsigned*)(ws + o_pack);
        float2*   gpay1   = (float2*)(ws + o_pay1);
        float2*   gpay2   = (float2*)(ws + o_pay2);
        unsigned* btab    = (unsigned*)(ws + o_btab);
        float2*   normals = (float2*)(ws + o_normals);
        float2*   partials= (float2*)(ws + base_need);

        l1_sort<<<NCH, 256, 0, stream>>>(
            nb, areas, dens, rest, q, (const float2*)dist,
            gpack, gpay1, gpay2, btab);
        passB<<<NBIN * G, 512, 0, stream>>>(btab, gpack, gpay1, partials, G);
        reduceG<<<(N_PART + 255) / 256, 256, 0, stream>>>(partials, normals, G);
        passD<<<NBIN * G, 512, 0, stream>>>(btab, gpack, gpay2, normals, partials, G);
        reduceG<<<(N_PART + 255) / 256, 256, 0, stream>>>(partials, (float2*)out, G);
        return;
    }

    // --- Fallback paths ---
    const size_t normals_pad = 1 << 20;
    float* normals  = (float*)d_ws;
    float* partials = (float*)((char*)d_ws + normals_pad);
    const size_t per_chunk = (size_t)FB_NP_PAD * 2 * sizeof(float);
    int C = 0;
    if (ws_size > normals_pad) {
        C = (int)((ws_size - normals_pad) / per_chunk);
        if (C > FB_C_TARGET) C = FB_C_TARGET;
    }

    if (C >= 4) {
        const int grid = FB_NBINS * C;
        fb_pass1_binned<<<grid, 1024, 0, stream>>>(
            nb, areas, dens, q, (const float2*)dist, partials, C);
        fb_reduce_partials<<<(N_PART + 255) / 256, 256, 0, stream>>>(partials, normals, C);
        fb_pass2_binned<<<grid, 1024, 0, stream>>>(
            nb, areas, rest, q, (const float2*)dist, (const float2*)normals, partials, C);
        fb_reduce_partials<<<(N_PART + 255) / 256, 256, 0, stream>>>(partials, out, C);
    } else {
        const int nv = 2 * N_PART;
        fb_zero2<<<(nv + 255) / 256, 256, 0, stream>>>(normals, out, nv);
        const int blocks = (N_EDGE + 255) / 256;
        fb_pass1_atomic<<<blocks, 256, 0, stream>>>(
            nb, areas, dens, q, (const float2*)dist, normals);
        fb_pass2_atomic<<<blocks, 256, 0, stream>>>(
            nb, areas, rest, q, (const float2*)dist, (const float2*)normals, out);
    }
}